// Round 5
// baseline (1033.029 us; speedup 1.0000x reference)
//
#include <hip/hip_runtime.h>
#include <stdint.h>

#define HID 256
#define CAP 16

typedef __attribute__((ext_vector_type(8))) short bf16x8;   // 8 bf16 (4 VGPRs)
typedef __attribute__((ext_vector_type(4))) float f32x4;
typedef __attribute__((ext_vector_type(2))) float f32x2;

__device__ __forceinline__ float bf2f(unsigned short u) {
    union { unsigned int i; float f; } v; v.i = ((unsigned int)u) << 16; return v.f;
}
__device__ __forceinline__ unsigned short f2bf(float f) {
    union { float f; unsigned int i; } v; v.f = f;
    unsigned int r = (v.i + 0x7fffu + ((v.i >> 16) & 1u)) >> 16;
    return (unsigned short)r;
}
// ---- software fp8 e4m3fn fallbacks (exact w.r.t. the hw path) ----
__device__ __forceinline__ float fp82f_sw(unsigned char b) {
    unsigned int s = (unsigned int)(b & 0x80) << 24;
    int e = (b >> 3) & 0xF;
    int m = b & 7;
    float v;
    if (e) v = __uint_as_float(((unsigned int)(e + 120) << 23) | ((unsigned int)m << 20));
    else   v = (float)m * 0.001953125f;
    return __uint_as_float(__float_as_uint(v) | s);
}
__device__ __forceinline__ unsigned char f2fp8_sw(float x) {
    unsigned int bits = __float_as_uint(x);
    unsigned char s = (unsigned char)((bits >> 24) & 0x80);
    float ax = fabsf(x);
    if (!(ax >= 0.001953125f)) {
        int n = (int)rintf(ax * 512.f);
        return s | (unsigned char)n;
    }
    if (ax >= 448.f) return s | 0x7E;
    int ex; float mant = frexpf(ax, &ex);
    int e = ex + 6;
    if (e >= 1) {
        int q = (int)rintf(mant * 16.f);
        if (q == 16) { q = 8; ++e; }
        if (e > 15 || (e == 15 && q > 14)) return s | 0x7E;
        return s | (unsigned char)((e << 3) | (q - 8));
    } else {
        int n = (int)rintf(ax * 512.f);
        if (n >= 8) return s | 0x08;
        return s | (unsigned char)n;
    }
}
// ---- hardware fp8 conversion (gfx950: OCP e4m3fn) ----
__device__ __forceinline__ unsigned char f2fp8(float x) {
#if __has_builtin(__builtin_amdgcn_cvt_pk_fp8_f32)
    return (unsigned char)(__builtin_amdgcn_cvt_pk_fp8_f32(x, x, 0, false) & 0xff);
#else
    return f2fp8_sw(x);
#endif
}
__device__ __forceinline__ f32x4 fp8x4_to_f32(unsigned int u) {
#if __has_builtin(__builtin_amdgcn_cvt_pk_f32_fp8)
    f32x2 a = __builtin_amdgcn_cvt_pk_f32_fp8(u, false);
    f32x2 b = __builtin_amdgcn_cvt_pk_f32_fp8(u, true);
    f32x4 r; r[0] = a.x; r[1] = a.y; r[2] = b.x; r[3] = b.y;
    return r;
#else
    f32x4 r;
    #pragma unroll
    for (int q = 0; q < 4; ++q) r[q] = fp82f_sw((u >> (8 * q)) & 0xff);
    return r;
#endif
}
// 8 fp8 bytes -> 8 bf16 (exact: every e4m3fn value is representable in bf16)
__device__ __forceinline__ bf16x8 fp8x8_to_bf16x8(uint2 raw) {
#if __has_builtin(__builtin_amdgcn_cvt_pk_f32_fp8)
    f32x2 p0 = __builtin_amdgcn_cvt_pk_f32_fp8(raw.x, false);
    f32x2 p1 = __builtin_amdgcn_cvt_pk_f32_fp8(raw.x, true);
    f32x2 p2 = __builtin_amdgcn_cvt_pk_f32_fp8(raw.y, false);
    f32x2 p3 = __builtin_amdgcn_cvt_pk_f32_fp8(raw.y, true);
    union { unsigned int u[4]; bf16x8 v; } cv;
    cv.u[0] = (__float_as_uint(p0.x) >> 16) | (__float_as_uint(p0.y) & 0xffff0000u);
    cv.u[1] = (__float_as_uint(p1.x) >> 16) | (__float_as_uint(p1.y) & 0xffff0000u);
    cv.u[2] = (__float_as_uint(p2.x) >> 16) | (__float_as_uint(p2.y) & 0xffff0000u);
    cv.u[3] = (__float_as_uint(p3.x) >> 16) | (__float_as_uint(p3.y) & 0xffff0000u);
    return cv.v;
#else
    union { unsigned short u[8]; bf16x8 v; } cv;
    #pragma unroll
    for (int q = 0; q < 4; ++q) cv.u[q]     = f2bf(fp82f_sw((raw.x >> (8 * q)) & 0xff));
    #pragma unroll
    for (int q = 0; q < 4; ++q) cv.u[4 + q] = f2bf(fp82f_sw((raw.y >> (8 * q)) & 0xff));
    return cv.v;
#endif
}

// async global->LDS, 16B per lane; LDS dest = wave-uniform base + lane*16
__device__ __forceinline__ void llds16(const void* g, void* l) {
    __builtin_amdgcn_global_load_lds(
        (const __attribute__((address_space(1))) void*)g,
        (__attribute__((address_space(3))) void*)l, 16, 0, 0);
}

// ---------------- utility / prep kernels ----------------

__global__ void k_zero_f(float* __restrict__ p, size_t n) {
    size_t i = (size_t)blockIdx.x * 256 + threadIdx.x;
    if (i < n) p[i] = 0.f;
}
__global__ void k_diag(float* __restrict__ out, float v) {
    if (blockIdx.x == 0 && threadIdx.x == 0) out[0] = v;
}

// one-shot init: zero cnt_lg[E], cnt_nd[N], cnt_t[N], gcnt[G]; gstart[G]=N
__global__ void k_init(int* __restrict__ cnt_lg, int E,
                       int* __restrict__ cnt_nd, int* __restrict__ cnt_t, int N,
                       int* __restrict__ gcnt, int* __restrict__ gstart, int G) {
    int i = blockIdx.x * 256 + threadIdx.x;
    if (i < E) cnt_lg[i] = 0;
    if (i < N) { cnt_nd[i] = 0; cnt_t[i] = 0; }
    if (i < G) { gcnt[i] = 0; gstart[i] = N; }
}

// alpha[v] = fp8( sum_{t in bkt_t[v]} tree_mess[t] )   (one wave per node, 4 cols/lane)
__global__ void k_alpha(const float* __restrict__ tm, const int* __restrict__ cnt,
                        const int* __restrict__ bkt, unsigned char* __restrict__ alpha, int N) {
    int wave = threadIdx.x >> 6, lane = threadIdx.x & 63;
    int v = blockIdx.x * 4 + wave;
    if (v >= N) return;
    int d = cnt[v]; if (d > CAP) d = CAP;
    f32x4 s = {0.f, 0.f, 0.f, 0.f};
    const int* bb = bkt + (size_t)v * CAP;
    for (int t = 0; t < d; ++t) {
        int r = bb[t];
        f32x4 x = *(const f32x4*)(tm + (size_t)r * HID + lane * 4);
        #pragma unroll
        for (int k = 0; k < 4; ++k) s[k] += x[k];
    }
    union { unsigned char b[4]; unsigned int u; } ov;
    #pragma unroll
    for (int k = 0; k < 4; ++k) ov.b[k] = f2fp8(s[k]);
    *(unsigned int*)(alpha + (size_t)v * HID + lane * 4) = ov.u;
}

// Wt_i[n][k] (256 x 64): k<40 -> W_i[k][n], else 0   (bf16)
__global__ void k_wt_i(const float* __restrict__ W, unsigned short* __restrict__ Wt) {
    int i = blockIdx.x * 256 + threadIdx.x;   // 256*64
    int n = i >> 6, k = i & 63;
    Wt[i] = f2bf((k < 40) ? W[k * HID + n] : 0.f);
}
// Wt_hi[n][k] (256 x 320): k<256 -> W_h[k][n]; k-256<40 -> W_i[k-256][n]; else 0
__global__ void k_wt_hi(const float* __restrict__ Wh, const float* __restrict__ Wi,
                        unsigned short* __restrict__ Wt) {
    int i = blockIdx.x * 256 + threadIdx.x;   // 256*320
    int n = i / 320, k = i % 320;
    float v;
    if (k < 256) v = Wh[(size_t)k * HID + n];
    else if (k < 296) v = Wi[(size_t)(k - 256) * HID + n];
    else v = 0.f;
    Wt[i] = f2bf(v);
}
// Wt_o[n][k] (256 x 320): k<256 -> W_o[35+k][n]; k-256<35 -> W_o[k-256][n]; else 0
__global__ void k_wt_o(const float* __restrict__ W, unsigned short* __restrict__ Wt) {
    int i = blockIdx.x * 256 + threadIdx.x;   // 256*320
    int n = i / 320, k = i % 320;
    float v;
    if (k < 256) v = W[(size_t)(35 + k) * HID + n];
    else if (k < 291) v = W[(size_t)(k - 256) * HID + n];
    else v = 0.f;
    Wt[i] = f2bf(v);
}

// A1[e][0..63] fp8: k<35 node_x[src][k], 35..39 bond_x[e][k-35], else 0
__global__ void k_a1(const float* __restrict__ nx, const float* __restrict__ bx,
                     const int* __restrict__ esrc, unsigned char* __restrict__ A1, int E) {
    int i = blockIdx.x * 256 + threadIdx.x;
    if (i >= E * 64) return;
    int e = i >> 6, k = i & 63;
    float v = 0.f;
    if (k < 35) v = nx[(size_t)esrc[e] * 35 + k];
    else if (k < 40) v = bx[(size_t)e * 5 + (k - 35)];
    A1[i] = f2fp8(v);
}

// X1[v][0..63] fp8: k<35 node_x[v][k], else 0
__global__ void k_x1(const float* __restrict__ nx, unsigned char* __restrict__ X1, int N) {
    int i = blockIdx.x * 256 + threadIdx.x;
    if (i >= N * 64) return;
    int v = i >> 6, k = i & 63;
    X1[i] = f2fp8((k < 35) ? nx[(size_t)v * 35 + k] : 0.f);
}

// bucket fill
__global__ void k_fill(const int* __restrict__ dst, const int* __restrict__ val,
                       int* __restrict__ cnt, int* __restrict__ bkt, int n, int useval) {
    int i = blockIdx.x * 256 + threadIdx.x;
    if (i >= n) return;
    int d = dst[i];
    int p = atomicAdd(&cnt[d], 1);
    if (p < CAP) bkt[(size_t)d * CAP + p] = useval ? val[i] : i;
}

__global__ void k_gfill(const int* __restrict__ gid, int* __restrict__ gstart,
                        int* __restrict__ gcnt, int N) {
    int i = blockIdx.x * 256 + threadIdx.x;
    if (i >= N) return;
    int g = gid[i];
    atomicAdd(&gcnt[g], 1);
    atomicMin(&gstart[g], i);
}

// ---------------- split-A GEMM with optional fused gather-staging ----------------
// C[M,256] = [Apart1 (K1 cols) | Aq (KTOT-K1 cols)] @ B[256][KTOT]^T  (B bf16, LDS-staged)
// BM=128, BN=256 (grid.y=1), 4 waves 2x2, per-wave 64x128, acc[4][8] f32x4.
// Schedule = the empirically-best R2 shape: per K-step {stage B -> barrier ->
// MFMA -> barrier}; A is resident in LDS for the whole K extent (staged once).
// FUSE==1 (loop GEMMs): A cols 0..K1-1 are NOT materialized in HBM. Each
//   16-lane group gathers alpha[esrc[row]] + sum msg[bkt[row]] in f32 (exact
//   k_accum order), quantizes to fp8, ds_writes into the swizzled A tile.
//   This deletes the separate k_accum kernel and accum's HBM write+read.
// FUSE==0: A part-1 staged via llds16 (WHOLEK: once; !WHOLEK: per K-step,
//   single seg buffer — used by the final GEMM to keep LDS at 48 KB).
// XOR swizzle (both-sides): chunk ^ (row&3) fp8 / ^(row&7) bf16 on source (or
// ds_write addr) and the same XOR at ds_read.
// EPI 0: relu(C); EPI 1: relu(C + bias[col]).  OUTF8: store fp8 else bf16.
template<int K1, int KTOT, int EPI, bool PF8, bool QF8, bool OUTF8, int FUSE, bool WHOLEK>
__global__ __launch_bounds__(256, 2)
void gemm7(const void* __restrict__ Ap, int lda1,
           const void* __restrict__ Aq, int lda2,
           const unsigned short* __restrict__ B, int M,
           void* __restrict__ out, const float* __restrict__ bias,
           const unsigned char* __restrict__ g_alpha, const int* __restrict__ g_idx,
           const int* __restrict__ g_cnt, const int* __restrict__ g_bkt)
{
    constexpr int NKC = KTOT / 64;
    constexpr int NK1 = K1 / 64;
    constexpr int S1  = PF8 ? 8192 : 16384;     // bytes per 64-col A segment
    constexpr int S2  = QF8 ? 8192 : 16384;
    constexpr int ATOT = WHOLEK ? (NK1 * S1 + (NKC - NK1) * S2) : (S1 > S2 ? S1 : S2);
    __shared__ unsigned char Als[ATOT];
    __shared__ unsigned char Bls[256 * 128];
    const int tid  = threadIdx.x;
    const int lane = tid & 63;
    const int wid  = tid >> 6;
    const int wm = wid & 1, wn = wid >> 1;
    const int row0 = blockIdx.x * 128;
    const int l15  = lane & 15;
    const int quad = lane >> 4;

    f32x4 acc[4][8] = {};

    const int sA8_r = lane >> 2, sA8_c = lane & 3;   // fp8 seg llds16: 16 rows/issue
    const int s16_r = lane >> 3, s16_c = lane & 7;   // bf16 seg llds16: 8 rows/issue

    auto aoff = [&](int kc) -> int {
        if (!WHOLEK) return 0;
        return (kc < NK1) ? kc * S1 : NK1 * S1 + (kc - NK1) * S2;
    };

    auto stageA_llds = [&](int kc, int dstoff) {
        const bool pPart = (kc < NK1);
        const void* As = pPart ? Ap : Aq;
        const int  lda  = pPart ? lda1 : lda2;
        const int  kofs = pPart ? kc * 64 : (kc - NK1) * 64;
        const bool f8   = pPart ? PF8 : QF8;
        if (f8) {
            #pragma unroll
            for (int t = 0; t < 2; ++t) {
                int r = wid * 32 + t * 16 + sA8_r;
                int ar = row0 + r; if (ar > M - 1) ar = M - 1;
                int ck = sA8_c ^ (r & 3);
                const unsigned char* g = (const unsigned char*)As + (size_t)ar * lda + kofs + ck * 16;
                llds16(g, &Als[dstoff + (wid * 32 + t * 16) * 64]);
            }
        } else {
            #pragma unroll
            for (int t = 0; t < 4; ++t) {
                int r = wid * 32 + t * 8 + s16_r;
                int ar = row0 + r; if (ar > M - 1) ar = M - 1;
                int ck = s16_c ^ (r & 7);
                const unsigned char* g = (const unsigned char*)As + ((size_t)ar * lda + kofs) * 2 + ck * 16;
                llds16(g, &Als[dstoff + (wid * 32 + t * 8) * 128]);
            }
        }
    };
    auto stageB = [&](int kc) {
        #pragma unroll
        for (int t = 0; t < 8; ++t) {
            int r = wid * 64 + t * 8 + s16_r;                  // 0..255
            int ck = s16_c ^ (r & 7);
            const unsigned char* g = (const unsigned char*)B + ((size_t)r * KTOT + kc * 64) * 2 + ck * 16;
            llds16(g, &Bls[(wid * 64 + t * 8) * 128]);
        }
    };

    // ---- stage A (whole-K resident) ----
    if (FUSE == 1) {
        // fused gather-stage of A cols 0..K1-1 (fp8): exact k_accum semantics.
        const unsigned char* msrc = (const unsigned char*)Ap;
        const int grp = tid >> 4, sl = tid & 15;
        #pragma unroll
        for (int rr = 0; rr < 8; ++rr) {
            int r = rr * 16 + grp;                 // 0..127
            int ar = row0 + r; if (ar > M - 1) ar = M - 1;
            int src = g_idx[ar];
            int d = g_cnt[ar]; if (d > CAP) d = CAP;
            uint4 au = *(const uint4*)(g_alpha + (size_t)src * HID + sl * 16);
            f32x4 s0 = fp8x4_to_f32(au.x);
            f32x4 s1 = fp8x4_to_f32(au.y);
            f32x4 s2 = fp8x4_to_f32(au.z);
            f32x4 s3 = fp8x4_to_f32(au.w);
            const int* bb = g_bkt + (size_t)ar * CAP;
            for (int t = 0; t < d; ++t) {
                uint4 mu = *(const uint4*)(msrc + (size_t)bb[t] * HID + sl * 16);
                f32x4 a0 = fp8x4_to_f32(mu.x), a1 = fp8x4_to_f32(mu.y);
                f32x4 a2 = fp8x4_to_f32(mu.z), a3 = fp8x4_to_f32(mu.w);
                #pragma unroll
                for (int k = 0; k < 4; ++k) { s0[k] += a0[k]; s1[k] += a1[k]; s2[k] += a2[k]; s3[k] += a3[k]; }
            }
            union { unsigned char b[16]; uint4 u; } ov;
            #pragma unroll
            for (int k = 0; k < 4; ++k) {
                ov.b[k]      = f2fp8(s0[k]);
                ov.b[4 + k]  = f2fp8(s1[k]);
                ov.b[8 + k]  = f2fp8(s2[k]);
                ov.b[12 + k] = f2fp8(s3[k]);
            }
            int seg = sl >> 2, ck = (sl & 3) ^ (r & 3);
            *(uint4*)&Als[seg * 8192 + r * 64 + ck * 16] = ov.u;
        }
        #pragma unroll
        for (int kc = NK1; kc < NKC; ++kc) stageA_llds(kc, aoff(kc));
    } else if (WHOLEK) {
        #pragma unroll
        for (int kc = 0; kc < NKC; ++kc) stageA_llds(kc, aoff(kc));
    } else {
        stageA_llds(0, 0);
    }
    stageB(0);
    __syncthreads();

    // ---- K-loop (R2 schedule: MFMA -> barrier -> stage next -> barrier) ----
    #pragma unroll
    for (int kc = 0; kc < NKC; ++kc) {
        const bool f8  = (kc < NK1) ? PF8 : QF8;
        const int ab = aoff(kc);
        #pragma unroll
        for (int kk = 0; kk < 64; kk += 32) {
            bf16x8 af[4];
            #pragma unroll
            for (int i = 0; i < 4; ++i) {
                int arow = wm * 64 + i * 16 + l15;
                if (f8) {
                    int ck = (kk >> 4) + (quad >> 1);
                    uint2 raw = *(const uint2*)&Als[ab + arow * 64 + ((ck ^ (arow & 3)) << 4) + ((quad & 1) << 3)];
                    af[i] = fp8x8_to_bf16x8(raw);
                } else {
                    int ck = (kk >> 3) + quad;
                    af[i] = *(const bf16x8*)&Als[ab + arow * 128 + ((ck ^ (arow & 7)) << 4)];
                }
            }
            #pragma unroll
            for (int j = 0; j < 8; ++j) {
                int brow = wn * 128 + j * 16 + l15;
                int ck = (kk >> 3) + quad;
                bf16x8 bfr = *(const bf16x8*)&Bls[brow * 128 + ((ck ^ (brow & 7)) << 4)];
                #pragma unroll
                for (int i = 0; i < 4; ++i)
                    acc[i][j] = __builtin_amdgcn_mfma_f32_16x16x32_bf16(af[i], bfr, acc[i][j], 0, 0, 0);
            }
        }
        if (kc + 1 < NKC) {
            __syncthreads();
            if (!WHOLEK) stageA_llds(kc + 1, 0);
            stageB(kc + 1);
            __syncthreads();
        }
    }

    // epilogue: C/D layout col = lane&15, row = quad*4 + reg
    #pragma unroll
    for (int i = 0; i < 4; ++i) {
        int rbase = row0 + wm * 64 + i * 16 + quad * 4;
        #pragma unroll
        for (int r = 0; r < 4; ++r) {
            int row = rbase + r;
            if (row >= M) continue;
            #pragma unroll
            for (int j = 0; j < 8; ++j) {
                int col = wn * 128 + j * 16 + l15;
                float v = acc[i][j][r];
                if (EPI == 1) v += bias[col];
                v = v > 0.f ? v : 0.f;
                if (OUTF8) ((unsigned char*)out)[(size_t)row * HID + col] = f2fp8(v);
                else       ((unsigned short*)out)[(size_t)row * HID + col] = f2bf(v);
            }
        }
    }
}

// ---------------- gather kernels ----------------

// Mb[v] = alpha[v] + sum_{e in bkt_nd[v]} msg[e]   (bf16 out) — 2 nodes/wave, 8B/lane
__global__ void k_mpa(const unsigned char* __restrict__ msg, const unsigned char* __restrict__ alpha,
                      const int* __restrict__ cnt, const int* __restrict__ bkt,
                      unsigned short* __restrict__ Mb, int N)
{
    int wave = threadIdx.x >> 6;
    int lane = threadIdx.x & 63;
    int sub  = lane >> 5;
    int sl   = lane & 31;
    int v = blockIdx.x * 8 + wave * 2 + sub;
    if (v >= N) return;
    int c = sl * 8;
    int d = cnt[v]; if (d > CAP) d = CAP;
    uint2 au = *(const uint2*)(alpha + (size_t)v * HID + c);
    f32x4 s0 = fp8x4_to_f32(au.x);
    f32x4 s1 = fp8x4_to_f32(au.y);
    const int* bb = bkt + (size_t)v * CAP;
    for (int base = 0; base < d; base += 4) {
        int4 bi = *(const int4*)(bb + base);
        int rem = d - base;
        int i0 = bi.x;
        int i1 = (rem > 1) ? bi.y : bi.x;
        int i2 = (rem > 2) ? bi.z : bi.x;
        int i3 = (rem > 3) ? bi.w : bi.x;
        uint2 m0 = *(const uint2*)(msg + (size_t)i0 * HID + c);
        uint2 m1 = *(const uint2*)(msg + (size_t)i1 * HID + c);
        uint2 m2 = *(const uint2*)(msg + (size_t)i2 * HID + c);
        uint2 m3 = *(const uint2*)(msg + (size_t)i3 * HID + c);
        {   f32x4 vx = fp8x4_to_f32(m0.x), vy = fp8x4_to_f32(m0.y);
            #pragma unroll
            for (int k = 0; k < 4; ++k) { s0[k] += vx[k]; s1[k] += vy[k]; } }
        if (rem > 1) { f32x4 vx = fp8x4_to_f32(m1.x), vy = fp8x4_to_f32(m1.y);
            #pragma unroll
            for (int k = 0; k < 4; ++k) { s0[k] += vx[k]; s1[k] += vy[k]; } }
        if (rem > 2) { f32x4 vx = fp8x4_to_f32(m2.x), vy = fp8x4_to_f32(m2.y);
            #pragma unroll
            for (int k = 0; k < 4; ++k) { s0[k] += vx[k]; s1[k] += vy[k]; } }
        if (rem > 3) { f32x4 vx = fp8x4_to_f32(m3.x), vy = fp8x4_to_f32(m3.y);
            #pragma unroll
            for (int k = 0; k < 4; ++k) { s0[k] += vx[k]; s1[k] += vy[k]; } }
    }
    union { unsigned short h[8]; uint4 u; } ov;
    #pragma unroll
    for (int k = 0; k < 4; ++k) { ov.h[k] = f2bf(s0[k]); ov.h[4 + k] = f2bf(s1[k]); }
    *(uint4*)(Mb + (size_t)v * HID + c) = ov.u;
}

// per-graph mean (graph_ids sorted -> contiguous rows)
__global__ void k_gmean(const unsigned short* __restrict__ h, const int* __restrict__ gstart,
                        const int* __restrict__ gcnt, float* __restrict__ out, int G) {
    int g = blockIdx.x;
    int c = threadIdx.x;
    int st = gstart[g], n = gcnt[g];
    float s = 0.f;
    for (int r = 0; r < n; ++r) s += bf2f(h[(size_t)(st + r) * HID + c]);
    out[(size_t)g * HID + c] = (n > 0) ? s / (float)n : 0.f;
}

// ---------------- launch ----------------
extern "C" void kernel_launch(void* const* d_in, const int* in_sizes, int n_in,
                              void* d_out, int out_size, void* d_ws, size_t ws_size,
                              hipStream_t stream)
{
    const float* node_x    = (const float*)d_in[0];
    const float* bond_x    = (const float*)d_in[1];
    const float* tree_mess = (const float*)d_in[2];
    const float* W_i       = (const float*)d_in[3];
    const float* W_h       = (const float*)d_in[4];
    const float* W_o       = (const float*)d_in[5];
    const float* b_o       = (const float*)d_in[6];
    const int* edge_src    = (const int*)d_in[7];
    const int* edge_dst    = (const int*)d_in[8];
    const int* lg_src      = (const int*)d_in[9];
    const int* lg_dst      = (const int*)d_in[10];
    const int* tgt_nodes   = (const int*)d_in[11];
    const int* graph_ids   = (const int*)d_in[12];

    const int N = in_sizes[0] / 35;
    const int E = in_sizes[1] / 5;
    const int T = in_sizes[2] / HID;
    const int L = in_sizes[9];
    const int G = out_size / HID;

    auto rup = [](size_t b) { return (b + 255) & ~(size_t)255; };
    const size_t szAcc = (size_t)E * HID;        // msgB fp8
    const size_t szMsg = (size_t)E * HID;        // msgA fp8
    const size_t szMbN = (size_t)N * HID * 2;    // Mb/h bf16
    const size_t R_acc = rup(szAcc > szMbN ? szAcc : szMbN);
    const size_t R_msg = rup(szMsg > szMbN ? szMsg : szMbN);
    const size_t R_al  = rup((size_t)N * HID);   // alpha fp8
    const size_t R_a1  = rup((size_t)E * 64);    // A1/X1 fp8
    const size_t need = R_acc + R_msg + R_al + R_a1
        + rup(256 * 64 * 2) + rup((size_t)256 * 320 * 2) * 2
        + rup((size_t)E * 4) + rup((size_t)E * CAP * 4)
        + rup((size_t)N * 4) + rup((size_t)N * CAP * 4)
        + rup((size_t)N * 4) + rup((size_t)N * CAP * 4)
        + rup((size_t)G * 4) * 2;

    if (need > ws_size) {
        k_zero_f<<<(out_size + 255) / 256, 256, 0, stream>>>((float*)d_out, (size_t)out_size);
        k_diag<<<1, 64, 0, stream>>>((float*)d_out, (float)(ws_size >> 20));
        return;
    }

    char* w = (char*)d_ws;
    auto alloc = [&](size_t bytes) { char* p = w; w += (bytes + 255) & ~(size_t)255; return p; };
    char* r_acc = (char*)alloc(R_acc);
    char* r_msg = (char*)alloc(R_msg);
    char* r_al  = (char*)alloc(R_al);
    char* r_a1  = (char*)alloc(R_a1);
    unsigned short* Wt_i  = (unsigned short*)alloc(256 * 64 * 2);
    unsigned short* Wt_hi = (unsigned short*)alloc((size_t)256 * 320 * 2);
    unsigned short* Wt_o  = (unsigned short*)alloc((size_t)256 * 320 * 2);
    int* cnt_lg = (int*)alloc((size_t)E * 4);
    int* bkt_lg = (int*)alloc((size_t)E * CAP * 4);
    int* cnt_nd = (int*)alloc((size_t)N * 4);
    int* bkt_nd = (int*)alloc((size_t)N * CAP * 4);
    int* cnt_t  = (int*)alloc((size_t)N * 4);
    int* bkt_t  = (int*)alloc((size_t)N * CAP * 4);
    int* gstart = (int*)alloc((size_t)G * 4);
    int* gcnt   = (int*)alloc((size_t)G * 4);

    unsigned char*  msgB  = (unsigned char*)r_acc;   // ping-pong buffer B
    unsigned short* Mb    = (unsigned short*)r_acc;  // reused after loop
    unsigned char*  msgA  = (unsigned char*)r_msg;   // ping-pong buffer A
    unsigned short* h     = (unsigned short*)r_msg;
    unsigned char*  alpha = (unsigned char*)r_al;
    unsigned char*  A1    = (unsigned char*)r_a1;
    unsigned char*  X1    = (unsigned char*)r_a1;

    // ---- init + buckets ----
    k_init<<<(E + 255) / 256, 256, 0, stream>>>(cnt_lg, E, cnt_nd, cnt_t, N, gcnt, gstart, G);

    k_wt_i<<<64, 256, 0, stream>>>(W_i, Wt_i);
    k_wt_hi<<<320, 256, 0, stream>>>(W_h, W_i, Wt_hi);
    k_wt_o<<<320, 256, 0, stream>>>(W_o, Wt_o);
    k_fill<<<(L + 255) / 256, 256, 0, stream>>>(lg_dst, lg_src, cnt_lg, bkt_lg, L, 1);
    k_fill<<<(E + 255) / 256, 256, 0, stream>>>(edge_dst, (const int*)nullptr, cnt_nd, bkt_nd, E, 0);
    k_fill<<<(T + 255) / 256, 256, 0, stream>>>(tgt_nodes, (const int*)nullptr, cnt_t, bkt_t, T, 0);
    k_gfill<<<(N + 255) / 256, 256, 0, stream>>>(graph_ids, gstart, gcnt, N);
    k_alpha<<<(N + 3) / 4, 256, 0, stream>>>(tree_mess, cnt_t, bkt_t, alpha, N);
    k_a1<<<(E * 64 + 255) / 256, 256, 0, stream>>>(node_x, bond_x, edge_src, A1, E);

    dim3 gE((E + 127) / 128, 1), gN((N + 127) / 128, 1);

    // msg0 = relu(A1 @ W_i) -> msgB   [fp8 out]
    gemm7<0, 64, 0, false, true, true, 0, true><<<gE, 256, 0, stream>>>(
        nullptr, 0, A1, 64, Wt_i, E, msgB, nullptr, nullptr, nullptr, nullptr, nullptr);

    // 3 loopy-BP iters, fused gather: msg_dst = relu([gather(alpha,msg_src)|A1] @ Wt_hi^T)
    for (int it = 0; it < 3; ++it) {
        const unsigned char* src = (it & 1) ? msgA : msgB;
        unsigned char*       dst = (it & 1) ? msgB : msgA;
        gemm7<256, 320, 0, true, true, true, 1, true><<<gE, 256, 0, stream>>>(
            src, 256, A1, 64, Wt_hi, E, dst, nullptr, alpha, edge_src, cnt_lg, bkt_lg);
    }
    // after 3 iters the live msg is msgA (= r_msg)

    // final: Mb = alpha + node-gather(msg) [bf16]; X1 = node_x pad; h = relu([Mb|X1] @ Wt_o^T + b_o)
    k_x1<<<(N * 64 + 255) / 256, 256, 0, stream>>>(node_x, X1, N);                 // A1 dead
    k_mpa<<<(N + 7) / 8, 256, 0, stream>>>(msgA, alpha, cnt_nd, bkt_nd, Mb, N);    // writes r_acc
    gemm7<256, 320, 1, false, true, false, 0, false><<<gN, 256, 0, stream>>>(
        Mb, 256, X1, 64, Wt_o, N, h, b_o, nullptr, nullptr, nullptr, nullptr);     // h in r_msg
    k_gmean<<<G, 256, 0, stream>>>(h, gstart, gcnt, (float*)d_out, G);
}

// Round 6
// 856.243 us; speedup vs baseline: 1.2065x; 1.2065x over previous
//
#include <hip/hip_runtime.h>
#include <stdint.h>

#define HID 256
#define CAP 16

typedef __attribute__((ext_vector_type(8))) short bf16x8;   // 8 bf16 (4 VGPRs)
typedef __attribute__((ext_vector_type(4))) float f32x4;
typedef __attribute__((ext_vector_type(2))) float f32x2;

__device__ __forceinline__ float bf2f(unsigned short u) {
    union { unsigned int i; float f; } v; v.i = ((unsigned int)u) << 16; return v.f;
}
__device__ __forceinline__ unsigned short f2bf(float f) {
    union { float f; unsigned int i; } v; v.f = f;
    unsigned int r = (v.i + 0x7fffu + ((v.i >> 16) & 1u)) >> 16;
    return (unsigned short)r;
}
// ---- software fp8 e4m3fn fallbacks (exact w.r.t. the hw path) ----
__device__ __forceinline__ float fp82f_sw(unsigned char b) {
    unsigned int s = (unsigned int)(b & 0x80) << 24;
    int e = (b >> 3) & 0xF;
    int m = b & 7;
    float v;
    if (e) v = __uint_as_float(((unsigned int)(e + 120) << 23) | ((unsigned int)m << 20));
    else   v = (float)m * 0.001953125f;
    return __uint_as_float(__float_as_uint(v) | s);
}
__device__ __forceinline__ unsigned char f2fp8_sw(float x) {
    unsigned int bits = __float_as_uint(x);
    unsigned char s = (unsigned char)((bits >> 24) & 0x80);
    float ax = fabsf(x);
    if (!(ax >= 0.001953125f)) {
        int n = (int)rintf(ax * 512.f);
        return s | (unsigned char)n;
    }
    if (ax >= 448.f) return s | 0x7E;
    int ex; float mant = frexpf(ax, &ex);
    int e = ex + 6;
    if (e >= 1) {
        int q = (int)rintf(mant * 16.f);
        if (q == 16) { q = 8; ++e; }
        if (e > 15 || (e == 15 && q > 14)) return s | 0x7E;
        return s | (unsigned char)((e << 3) | (q - 8));
    } else {
        int n = (int)rintf(ax * 512.f);
        if (n >= 8) return s | 0x08;
        return s | (unsigned char)n;
    }
}
// ---- hardware fp8 conversion (gfx950: OCP e4m3fn) ----
__device__ __forceinline__ unsigned char f2fp8(float x) {
#if __has_builtin(__builtin_amdgcn_cvt_pk_fp8_f32)
    return (unsigned char)(__builtin_amdgcn_cvt_pk_fp8_f32(x, x, 0, false) & 0xff);
#else
    return f2fp8_sw(x);
#endif
}
__device__ __forceinline__ f32x4 fp8x4_to_f32(unsigned int u) {
#if __has_builtin(__builtin_amdgcn_cvt_pk_f32_fp8)
    f32x2 a = __builtin_amdgcn_cvt_pk_f32_fp8(u, false);
    f32x2 b = __builtin_amdgcn_cvt_pk_f32_fp8(u, true);
    f32x4 r; r[0] = a.x; r[1] = a.y; r[2] = b.x; r[3] = b.y;
    return r;
#else
    f32x4 r;
    #pragma unroll
    for (int q = 0; q < 4; ++q) r[q] = fp82f_sw((u >> (8 * q)) & 0xff);
    return r;
#endif
}
// 8 fp8 bytes -> 8 bf16 (exact: every e4m3fn value is representable in bf16)
__device__ __forceinline__ bf16x8 fp8x8_to_bf16x8(uint2 raw) {
#if __has_builtin(__builtin_amdgcn_cvt_pk_f32_fp8)
    f32x2 p0 = __builtin_amdgcn_cvt_pk_f32_fp8(raw.x, false);
    f32x2 p1 = __builtin_amdgcn_cvt_pk_f32_fp8(raw.x, true);
    f32x2 p2 = __builtin_amdgcn_cvt_pk_f32_fp8(raw.y, false);
    f32x2 p3 = __builtin_amdgcn_cvt_pk_f32_fp8(raw.y, true);
    union { unsigned int u[4]; bf16x8 v; } cv;
    cv.u[0] = (__float_as_uint(p0.x) >> 16) | (__float_as_uint(p0.y) & 0xffff0000u);
    cv.u[1] = (__float_as_uint(p1.x) >> 16) | (__float_as_uint(p1.y) & 0xffff0000u);
    cv.u[2] = (__float_as_uint(p2.x) >> 16) | (__float_as_uint(p2.y) & 0xffff0000u);
    cv.u[3] = (__float_as_uint(p3.x) >> 16) | (__float_as_uint(p3.y) & 0xffff0000u);
    return cv.v;
#else
    union { unsigned short u[8]; bf16x8 v; } cv;
    #pragma unroll
    for (int q = 0; q < 4; ++q) cv.u[q]     = f2bf(fp82f_sw((raw.x >> (8 * q)) & 0xff));
    #pragma unroll
    for (int q = 0; q < 4; ++q) cv.u[4 + q] = f2bf(fp82f_sw((raw.y >> (8 * q)) & 0xff));
    return cv.v;
#endif
}

// async global->LDS, 16B per lane; LDS dest = wave-uniform base + lane*16
__device__ __forceinline__ void llds16(const void* g, void* l) {
    __builtin_amdgcn_global_load_lds(
        (const __attribute__((address_space(1))) void*)g,
        (__attribute__((address_space(3))) void*)l, 16, 0, 0);
}

// ---------------- utility / prep kernels ----------------

__global__ void k_zero_f(float* __restrict__ p, size_t n) {
    size_t i = (size_t)blockIdx.x * 256 + threadIdx.x;
    if (i < n) p[i] = 0.f;
}
__global__ void k_diag(float* __restrict__ out, float v) {
    if (blockIdx.x == 0 && threadIdx.x == 0) out[0] = v;
}

// one-shot init: zero cnt_lg[E], cnt_nd[N], cnt_t[N], gcnt[G]; gstart[G]=N
__global__ void k_init(int* __restrict__ cnt_lg, int E,
                       int* __restrict__ cnt_nd, int* __restrict__ cnt_t, int N,
                       int* __restrict__ gcnt, int* __restrict__ gstart, int G) {
    int i = blockIdx.x * 256 + threadIdx.x;
    if (i < E) cnt_lg[i] = 0;
    if (i < N) { cnt_nd[i] = 0; cnt_t[i] = 0; }
    if (i < G) { gcnt[i] = 0; gstart[i] = N; }
}

// alpha[v] = fp8( sum_{t in bkt_t[v]} tree_mess[t] )   (one wave per node, 4 cols/lane)
__global__ void k_alpha(const float* __restrict__ tm, const int* __restrict__ cnt,
                        const int* __restrict__ bkt, unsigned char* __restrict__ alpha, int N) {
    int wave = threadIdx.x >> 6, lane = threadIdx.x & 63;
    int v = blockIdx.x * 4 + wave;
    if (v >= N) return;
    int d = cnt[v]; if (d > CAP) d = CAP;
    f32x4 s = {0.f, 0.f, 0.f, 0.f};
    const int* bb = bkt + (size_t)v * CAP;
    for (int t = 0; t < d; ++t) {
        int r = bb[t];
        f32x4 x = *(const f32x4*)(tm + (size_t)r * HID + lane * 4);
        #pragma unroll
        for (int k = 0; k < 4; ++k) s[k] += x[k];
    }
    union { unsigned char b[4]; unsigned int u; } ov;
    #pragma unroll
    for (int k = 0; k < 4; ++k) ov.b[k] = f2fp8(s[k]);
    *(unsigned int*)(alpha + (size_t)v * HID + lane * 4) = ov.u;
}

// Wt_i[n][k] (256 x 64): k<40 -> W_i[k][n], else 0   (bf16)
__global__ void k_wt_i(const float* __restrict__ W, unsigned short* __restrict__ Wt) {
    int i = blockIdx.x * 256 + threadIdx.x;   // 256*64
    int n = i >> 6, k = i & 63;
    Wt[i] = f2bf((k < 40) ? W[k * HID + n] : 0.f);
}
// Wt_hi[n][k] (256 x 320): k<256 -> W_h[k][n]; k-256<40 -> W_i[k-256][n]; else 0
__global__ void k_wt_hi(const float* __restrict__ Wh, const float* __restrict__ Wi,
                        unsigned short* __restrict__ Wt) {
    int i = blockIdx.x * 256 + threadIdx.x;   // 256*320
    int n = i / 320, k = i % 320;
    float v;
    if (k < 256) v = Wh[(size_t)k * HID + n];
    else if (k < 296) v = Wi[(size_t)(k - 256) * HID + n];
    else v = 0.f;
    Wt[i] = f2bf(v);
}
// Wt_o[n][k] (256 x 320): k<256 -> W_o[35+k][n]; k-256<35 -> W_o[k-256][n]; else 0
__global__ void k_wt_o(const float* __restrict__ W, unsigned short* __restrict__ Wt) {
    int i = blockIdx.x * 256 + threadIdx.x;   // 256*320
    int n = i / 320, k = i % 320;
    float v;
    if (k < 256) v = W[(size_t)(35 + k) * HID + n];
    else if (k < 291) v = W[(size_t)(k - 256) * HID + n];
    else v = 0.f;
    Wt[i] = f2bf(v);
}

// A1[e][0..63] fp8: k<35 node_x[src][k], 35..39 bond_x[e][k-35], else 0
__global__ void k_a1(const float* __restrict__ nx, const float* __restrict__ bx,
                     const int* __restrict__ esrc, unsigned char* __restrict__ A1, int E) {
    int i = blockIdx.x * 256 + threadIdx.x;
    if (i >= E * 64) return;
    int e = i >> 6, k = i & 63;
    float v = 0.f;
    if (k < 35) v = nx[(size_t)esrc[e] * 35 + k];
    else if (k < 40) v = bx[(size_t)e * 5 + (k - 35)];
    A1[i] = f2fp8(v);
}

// X1[v][0..63] fp8: k<35 node_x[v][k], else 0
__global__ void k_x1(const float* __restrict__ nx, unsigned char* __restrict__ X1, int N) {
    int i = blockIdx.x * 256 + threadIdx.x;
    if (i >= N * 64) return;
    int v = i >> 6, k = i & 63;
    X1[i] = f2fp8((k < 35) ? nx[(size_t)v * 35 + k] : 0.f);
}

// bucket fill
__global__ void k_fill(const int* __restrict__ dst, const int* __restrict__ val,
                       int* __restrict__ cnt, int* __restrict__ bkt, int n, int useval) {
    int i = blockIdx.x * 256 + threadIdx.x;
    if (i >= n) return;
    int d = dst[i];
    int p = atomicAdd(&cnt[d], 1);
    if (p < CAP) bkt[(size_t)d * CAP + p] = useval ? val[i] : i;
}

__global__ void k_gfill(const int* __restrict__ gid, int* __restrict__ gstart,
                        int* __restrict__ gcnt, int N) {
    int i = blockIdx.x * 256 + threadIdx.x;
    if (i >= N) return;
    int g = gid[i];
    atomicAdd(&gcnt[g], 1);
    atomicMin(&gstart[g], i);
}

// ---------------- split-A GEMM, m97 staging, 128x256 tile (R2 proven: 79.4us) ----------------
// C[M,256] = [Ap (K1 cols) | Aq (KTOT-K1 cols)] @ B[256][KTOT]^T   (B bf16)
// BM=128, BN=256 (full HID -> grid.y == 1): each A element staged/converted once
// per block; each barrier pair covers the full 2x MFMA work.
// 4 waves 2x2 -> per-wave 64x128 output, acc[4][8] f32x4.
// Staging: __builtin_amdgcn_global_load_lds width=16 (async). LDS dest linear;
// bank conflicts avoided by XOR-swizzling the per-lane GLOBAL source chunk
// (ck ^ (row&7) for 128B rows, ^(row&3) for 64B fp8 rows) and applying the same
// XOR on the ds_read address (both-sides-or-neither; XOR stays inside a row).
// fp8 A stays fp8 in LDS; converted to bf16 at fragment read.
// EPI 0: relu(C); EPI 1: relu(C + bias[col]).  OUTF8: store fp8 else bf16.
template<int K1, int KTOT, int EPI, bool PF8, bool QF8, bool OUTF8>
__global__ __launch_bounds__(256, 2)
void gemm4(const void* __restrict__ Ap, int lda1,
           const void* __restrict__ Aq, int lda2,
           const unsigned short* __restrict__ B, int M,
           void* __restrict__ out, const float* __restrict__ bias)
{
    constexpr int NKC = KTOT / 64;
    __shared__ unsigned char Als[128 * 128];   // fp8: [128][64B]; bf16: [128][128B]
    __shared__ unsigned char Bls[256 * 128];   // bf16 [256][128B]
    const int tid  = threadIdx.x;
    const int lane = tid & 63;
    const int wid  = tid >> 6;
    const int wm = wid & 1, wn = wid >> 1;
    const int row0 = blockIdx.x * 128;
    const int l15  = lane & 15;
    const int quad = lane >> 4;

    f32x4 acc[4][8] = {};

    // staging lane coords
    const int sA8_r = lane >> 2, sA8_c = lane & 3;   // fp8 A: 16 rows/issue, 4 chunks/row
    const int s16_r = lane >> 3, s16_c = lane & 7;   // 128B rows: 8 rows/issue, 8 chunks/row

    #pragma unroll
    for (int kc = 0; kc < NKC; ++kc) {
        const bool pPart = (kc * 64 < K1);
        const void* As = pPart ? Ap : Aq;
        const int  lda  = pPart ? lda1 : lda2;     // in elements of the A dtype
        const int  kofs = pPart ? kc * 64 : kc * 64 - K1;
        const bool f8   = pPart ? PF8 : QF8;

        // ---- stage A tile (async) ----
        if (f8) {
            #pragma unroll
            for (int t = 0; t < 2; ++t) {
                int r = wid * 32 + t * 16 + sA8_r;            // 0..127
                int ar = row0 + r; if (ar > M - 1) ar = M - 1;
                int ck = sA8_c ^ (r & 3);                      // source chunk (16B units)
                const unsigned char* g = (const unsigned char*)As + (size_t)ar * lda + kofs + ck * 16;
                llds16(g, &Als[(wid * 32 + t * 16) * 64]);
            }
        } else {
            #pragma unroll
            for (int t = 0; t < 4; ++t) {
                int r = wid * 32 + t * 8 + s16_r;
                int ar = row0 + r; if (ar > M - 1) ar = M - 1;
                int ck = s16_c ^ (r & 7);
                const unsigned char* g = (const unsigned char*)As + ((size_t)ar * lda + kofs) * 2 + ck * 16;
                llds16(g, &Als[(wid * 32 + t * 8) * 128]);
            }
        }
        // ---- stage B tile (async): all 256 rows of B[256][KTOT] ----
        #pragma unroll
        for (int t = 0; t < 8; ++t) {
            int r = wid * 64 + t * 8 + s16_r;                  // 0..255
            int ck = s16_c ^ (r & 7);
            const unsigned char* g = (const unsigned char*)B + ((size_t)r * KTOT + kc * 64) * 2 + ck * 16;
            llds16(g, &Bls[(wid * 64 + t * 8) * 128]);
        }
        __syncthreads();   // compiler drains vmcnt(0) before s_barrier -> tile resident

        // ---- MFMA phase ----
        #pragma unroll
        for (int kk = 0; kk < 64; kk += 32) {
            bf16x8 af[4];
            #pragma unroll
            for (int i = 0; i < 4; ++i) {
                int arow = wm * 64 + i * 16 + l15;
                if (f8) {
                    int ck = (kk >> 4) + (quad >> 1);          // 0..3
                    uint2 raw = *(const uint2*)&Als[arow * 64 + ((ck ^ (arow & 3)) << 4) + ((quad & 1) << 3)];
                    af[i] = fp8x8_to_bf16x8(raw);
                } else {
                    int ck = (kk >> 3) + quad;                 // 0..7
                    af[i] = *(const bf16x8*)&Als[arow * 128 + ((ck ^ (arow & 7)) << 4)];
                }
            }
            #pragma unroll
            for (int j = 0; j < 8; ++j) {
                int brow = wn * 128 + j * 16 + l15;
                int ck = (kk >> 3) + quad;
                bf16x8 bfr = *(const bf16x8*)&Bls[brow * 128 + ((ck ^ (brow & 7)) << 4)];
                #pragma unroll
                for (int i = 0; i < 4; ++i)
                    acc[i][j] = __builtin_amdgcn_mfma_f32_16x16x32_bf16(af[i], bfr, acc[i][j], 0, 0, 0);
            }
        }
        if (kc + 1 < NKC) __syncthreads();   // protect LDS before next stage
    }

    // epilogue: C/D layout col = lane&15, row = quad*4 + reg
    #pragma unroll
    for (int i = 0; i < 4; ++i) {
        int rbase = row0 + wm * 64 + i * 16 + quad * 4;
        #pragma unroll
        for (int r = 0; r < 4; ++r) {
            int row = rbase + r;
            if (row >= M) continue;
            #pragma unroll
            for (int j = 0; j < 8; ++j) {
                int col = wn * 128 + j * 16 + l15;
                float v = acc[i][j][r];
                if (EPI == 1) v += bias[col];
                v = v > 0.f ? v : 0.f;
                if (OUTF8) ((unsigned char*)out)[(size_t)row * HID + col] = f2fp8(v);
                else       ((unsigned short*)out)[(size_t)row * HID + col] = f2bf(v);
            }
        }
    }
}

// ---------------- gather kernels ----------------

// accum[e] = alpha[esrc[e]] + sum_{j in bkt[e]} msg[j]   (fp8 out)
// 4 edges per wave: 16 lanes x 16B per edge row (uint4), high-occupancy TLP.
__global__ void k_accum(const unsigned char* __restrict__ msg, const unsigned char* __restrict__ alpha,
                        const int* __restrict__ esrc, const int* __restrict__ cnt,
                        const int* __restrict__ bkt, unsigned char* __restrict__ accum, int E)
{
    int tid  = threadIdx.x;
    int lane = tid & 63, wave = tid >> 6;
    int sub  = lane >> 4;            // 0..3: which edge in this wave
    int sl   = lane & 15;
    int e = blockIdx.x * 16 + wave * 4 + sub;
    if (e >= E) return;
    int c = sl * 16;
    int src = esrc[e];
    int d = cnt[e]; if (d > CAP) d = CAP;
    uint4 au = *(const uint4*)(alpha + (size_t)src * HID + c);
    f32x4 s0 = fp8x4_to_f32(au.x);
    f32x4 s1 = fp8x4_to_f32(au.y);
    f32x4 s2 = fp8x4_to_f32(au.z);
    f32x4 s3 = fp8x4_to_f32(au.w);
    const int* bb = bkt + (size_t)e * CAP;
    for (int base = 0; base < d; base += 4) {
        int4 bi = *(const int4*)(bb + base);
        int rem = d - base;
        int i0 = bi.x;
        int i1 = (rem > 1) ? bi.y : bi.x;
        int i2 = (rem > 2) ? bi.z : bi.x;
        int i3 = (rem > 3) ? bi.w : bi.x;
        uint4 m0 = *(const uint4*)(msg + (size_t)i0 * HID + c);
        uint4 m1 = *(const uint4*)(msg + (size_t)i1 * HID + c);
        uint4 m2 = *(const uint4*)(msg + (size_t)i2 * HID + c);
        uint4 m3 = *(const uint4*)(msg + (size_t)i3 * HID + c);
        {   f32x4 a0 = fp8x4_to_f32(m0.x), a1 = fp8x4_to_f32(m0.y), a2 = fp8x4_to_f32(m0.z), a3 = fp8x4_to_f32(m0.w);
            #pragma unroll
            for (int k = 0; k < 4; ++k) { s0[k] += a0[k]; s1[k] += a1[k]; s2[k] += a2[k]; s3[k] += a3[k]; } }
        if (rem > 1) { f32x4 a0 = fp8x4_to_f32(m1.x), a1 = fp8x4_to_f32(m1.y), a2 = fp8x4_to_f32(m1.z), a3 = fp8x4_to_f32(m1.w);
            #pragma unroll
            for (int k = 0; k < 4; ++k) { s0[k] += a0[k]; s1[k] += a1[k]; s2[k] += a2[k]; s3[k] += a3[k]; } }
        if (rem > 2) { f32x4 a0 = fp8x4_to_f32(m2.x), a1 = fp8x4_to_f32(m2.y), a2 = fp8x4_to_f32(m2.z), a3 = fp8x4_to_f32(m2.w);
            #pragma unroll
            for (int k = 0; k < 4; ++k) { s0[k] += a0[k]; s1[k] += a1[k]; s2[k] += a2[k]; s3[k] += a3[k]; } }
        if (rem > 3) { f32x4 a0 = fp8x4_to_f32(m3.x), a1 = fp8x4_to_f32(m3.y), a2 = fp8x4_to_f32(m3.z), a3 = fp8x4_to_f32(m3.w);
            #pragma unroll
            for (int k = 0; k < 4; ++k) { s0[k] += a0[k]; s1[k] += a1[k]; s2[k] += a2[k]; s3[k] += a3[k]; } }
    }
    union { unsigned char b[16]; uint4 u; } ov;
    #pragma unroll
    for (int k = 0; k < 4; ++k) {
        ov.b[k]      = f2fp8(s0[k]);
        ov.b[4 + k]  = f2fp8(s1[k]);
        ov.b[8 + k]  = f2fp8(s2[k]);
        ov.b[12 + k] = f2fp8(s3[k]);
    }
    *(uint4*)(accum + (size_t)e * HID + c) = ov.u;
}

// Mb[v] = alpha[v] + sum_{e in bkt_nd[v]} msg[e]   (bf16 out) — 2 nodes/wave, 8B/lane
__global__ void k_mpa(const unsigned char* __restrict__ msg, const unsigned char* __restrict__ alpha,
                      const int* __restrict__ cnt, const int* __restrict__ bkt,
                      unsigned short* __restrict__ Mb, int N)
{
    int wave = threadIdx.x >> 6;
    int lane = threadIdx.x & 63;
    int sub  = lane >> 5;
    int sl   = lane & 31;
    int v = blockIdx.x * 8 + wave * 2 + sub;
    if (v >= N) return;
    int c = sl * 8;
    int d = cnt[v]; if (d > CAP) d = CAP;
    uint2 au = *(const uint2*)(alpha + (size_t)v * HID + c);
    f32x4 s0 = fp8x4_to_f32(au.x);
    f32x4 s1 = fp8x4_to_f32(au.y);
    const int* bb = bkt + (size_t)v * CAP;
    for (int base = 0; base < d; base += 4) {
        int4 bi = *(const int4*)(bb + base);
        int rem = d - base;
        int i0 = bi.x;
        int i1 = (rem > 1) ? bi.y : bi.x;
        int i2 = (rem > 2) ? bi.z : bi.x;
        int i3 = (rem > 3) ? bi.w : bi.x;
        uint2 m0 = *(const uint2*)(msg + (size_t)i0 * HID + c);
        uint2 m1 = *(const uint2*)(msg + (size_t)i1 * HID + c);
        uint2 m2 = *(const uint2*)(msg + (size_t)i2 * HID + c);
        uint2 m3 = *(const uint2*)(msg + (size_t)i3 * HID + c);
        {   f32x4 vx = fp8x4_to_f32(m0.x), vy = fp8x4_to_f32(m0.y);
            #pragma unroll
            for (int k = 0; k < 4; ++k) { s0[k] += vx[k]; s1[k] += vy[k]; } }
        if (rem > 1) { f32x4 vx = fp8x4_to_f32(m1.x), vy = fp8x4_to_f32(m1.y);
            #pragma unroll
            for (int k = 0; k < 4; ++k) { s0[k] += vx[k]; s1[k] += vy[k]; } }
        if (rem > 2) { f32x4 vx = fp8x4_to_f32(m2.x), vy = fp8x4_to_f32(m2.y);
            #pragma unroll
            for (int k = 0; k < 4; ++k) { s0[k] += vx[k]; s1[k] += vy[k]; } }
        if (rem > 3) { f32x4 vx = fp8x4_to_f32(m3.x), vy = fp8x4_to_f32(m3.y);
            #pragma unroll
            for (int k = 0; k < 4; ++k) { s0[k] += vx[k]; s1[k] += vy[k]; } }
    }
    union { unsigned short h[8]; uint4 u; } ov;
    #pragma unroll
    for (int k = 0; k < 4; ++k) { ov.h[k] = f2bf(s0[k]); ov.h[4 + k] = f2bf(s1[k]); }
    *(uint4*)(Mb + (size_t)v * HID + c) = ov.u;
}

// per-graph mean (graph_ids sorted -> contiguous rows)
__global__ void k_gmean(const unsigned short* __restrict__ h, const int* __restrict__ gstart,
                        const int* __restrict__ gcnt, float* __restrict__ out, int G) {
    int g = blockIdx.x;
    int c = threadIdx.x;
    int st = gstart[g], n = gcnt[g];
    float s = 0.f;
    for (int r = 0; r < n; ++r) s += bf2f(h[(size_t)(st + r) * HID + c]);
    out[(size_t)g * HID + c] = (n > 0) ? s / (float)n : 0.f;
}

// ---------------- launch ----------------
extern "C" void kernel_launch(void* const* d_in, const int* in_sizes, int n_in,
                              void* d_out, int out_size, void* d_ws, size_t ws_size,
                              hipStream_t stream)
{
    const float* node_x    = (const float*)d_in[0];
    const float* bond_x    = (const float*)d_in[1];
    const float* tree_mess = (const float*)d_in[2];
    const float* W_i       = (const float*)d_in[3];
    const float* W_h       = (const float*)d_in[4];
    const float* W_o       = (const float*)d_in[5];
    const float* b_o       = (const float*)d_in[6];
    const int* edge_src    = (const int*)d_in[7];
    const int* edge_dst    = (const int*)d_in[8];
    const int* lg_src      = (const int*)d_in[9];
    const int* lg_dst      = (const int*)d_in[10];
    const int* tgt_nodes   = (const int*)d_in[11];
    const int* graph_ids   = (const int*)d_in[12];

    const int N = in_sizes[0] / 35;
    const int E = in_sizes[1] / 5;
    const int T = in_sizes[2] / HID;
    const int L = in_sizes[9];
    const int G = out_size / HID;

    auto rup = [](size_t b) { return (b + 255) & ~(size_t)255; };
    const size_t szAcc = (size_t)E * HID;        // accum fp8
    const size_t szMsg = (size_t)E * HID;        // msg fp8
    const size_t szMbN = (size_t)N * HID * 2;    // Mb/h bf16
    const size_t R_acc = rup(szAcc > szMbN ? szAcc : szMbN);
    const size_t R_msg = rup(szMsg > szMbN ? szMsg : szMbN);
    const size_t R_al  = rup((size_t)N * HID);   // alpha fp8
    const size_t R_a1  = rup((size_t)E * 64);    // A1/X1 fp8
    const size_t need = R_acc + R_msg + R_al + R_a1
        + rup(256 * 64 * 2) + rup((size_t)256 * 320 * 2) * 2
        + rup((size_t)E * 4) + rup((size_t)E * CAP * 4)
        + rup((size_t)N * 4) + rup((size_t)N * CAP * 4)
        + rup((size_t)N * 4) + rup((size_t)N * CAP * 4)
        + rup((size_t)G * 4) * 2;

    if (need > ws_size) {
        k_zero_f<<<(out_size + 255) / 256, 256, 0, stream>>>((float*)d_out, (size_t)out_size);
        k_diag<<<1, 64, 0, stream>>>((float*)d_out, (float)(ws_size >> 20));
        return;
    }

    char* w = (char*)d_ws;
    auto alloc = [&](size_t bytes) { char* p = w; w += (bytes + 255) & ~(size_t)255; return p; };
    char* r_acc = (char*)alloc(R_acc);
    char* r_msg = (char*)alloc(R_msg);
    char* r_al  = (char*)alloc(R_al);
    char* r_a1  = (char*)alloc(R_a1);
    unsigned short* Wt_i  = (unsigned short*)alloc(256 * 64 * 2);
    unsigned short* Wt_hi = (unsigned short*)alloc((size_t)256 * 320 * 2);
    unsigned short* Wt_o  = (unsigned short*)alloc((size_t)256 * 320 * 2);
    int* cnt_lg = (int*)alloc((size_t)E * 4);
    int* bkt_lg = (int*)alloc((size_t)E * CAP * 4);
    int* cnt_nd = (int*)alloc((size_t)N * 4);
    int* bkt_nd = (int*)alloc((size_t)N * CAP * 4);
    int* cnt_t  = (int*)alloc((size_t)N * 4);
    int* bkt_t  = (int*)alloc((size_t)N * CAP * 4);
    int* gstart = (int*)alloc((size_t)G * 4);
    int* gcnt   = (int*)alloc((size_t)G * 4);

    unsigned char*  accum = (unsigned char*)r_acc;
    unsigned short* Mb    = (unsigned short*)r_acc;
    unsigned char*  msg   = (unsigned char*)r_msg;
    unsigned short* h     = (unsigned short*)r_msg;
    unsigned char*  alpha = (unsigned char*)r_al;
    unsigned char*  A1    = (unsigned char*)r_a1;
    unsigned char*  X1    = (unsigned char*)r_a1;

    // ---- init + buckets ----
    k_init<<<(E + 255) / 256, 256, 0, stream>>>(cnt_lg, E, cnt_nd, cnt_t, N, gcnt, gstart, G);

    k_wt_i<<<64, 256, 0, stream>>>(W_i, Wt_i);
    k_wt_hi<<<320, 256, 0, stream>>>(W_h, W_i, Wt_hi);
    k_wt_o<<<320, 256, 0, stream>>>(W_o, Wt_o);
    k_fill<<<(L + 255) / 256, 256, 0, stream>>>(lg_dst, lg_src, cnt_lg, bkt_lg, L, 1);
    k_fill<<<(E + 255) / 256, 256, 0, stream>>>(edge_dst, (const int*)nullptr, cnt_nd, bkt_nd, E, 0);
    k_fill<<<(T + 255) / 256, 256, 0, stream>>>(tgt_nodes, (const int*)nullptr, cnt_t, bkt_t, T, 0);
    k_gfill<<<(N + 255) / 256, 256, 0, stream>>>(graph_ids, gstart, gcnt, N);
    k_alpha<<<(N + 3) / 4, 256, 0, stream>>>(tree_mess, cnt_t, bkt_t, alpha, N);
    k_a1<<<(E * 64 + 255) / 256, 256, 0, stream>>>(node_x, bond_x, edge_src, A1, E);

    dim3 gE((E + 127) / 128, 1), gN((N + 127) / 128, 1);

    // msg0 = relu(A1 @ W_i)   [fp8 out]
    gemm4<0, 64, 0, false, true, true><<<gE, 256, 0, stream>>>(nullptr, 0, A1, 64, Wt_i, E, msg, nullptr);

    // 3 loopy-BP iters: accum = alpha[src] + gather(msg); msg = relu([accum|A1] @ Wt_hi^T)
    for (int it = 0; it < 3; ++it) {
        k_accum<<<(E + 15) / 16, 256, 0, stream>>>(msg, alpha, edge_src, cnt_lg, bkt_lg, accum, E);
        gemm4<256, 320, 0, true, true, true><<<gE, 256, 0, stream>>>(accum, 256, A1, 64, Wt_hi, E, msg, nullptr);
    }

    // final: Mb = alpha + node-gather(msg) [bf16]; X1 = node_x pad; h = relu([Mb|X1] @ Wt_o^T + b_o)
    k_x1<<<(N * 64 + 255) / 256, 256, 0, stream>>>(node_x, X1, N);                 // A1 dead
    k_mpa<<<(N + 7) / 8, 256, 0, stream>>>(msg, alpha, cnt_nd, bkt_nd, Mb, N);     // accum dead
    gemm4<256, 320, 1, false, true, false><<<gN, 256, 0, stream>>>(Mb, 256, X1, 64, Wt_o, N, h, b_o); // msg dead
    k_gmean<<<G, 256, 0, stream>>>(h, gstart, gcnt, (float*)d_out, G);
}